// Round 1
// baseline (935.461 us; speedup 1.0000x reference)
//
#include <hip/hip_runtime.h>

#define HIDDEN 128
#define NBUCKETS 20

// y[i][j] = sum_k x[i][k] * W1[k][j]        (threads 0..127)
// z[i][j] = sum_k x[i][k] * W1[128+k][j]    (threads 128..255)
__global__ void precompute_yz_kernel(const float* __restrict__ x,
                                     const float* __restrict__ W1,
                                     float* __restrict__ y,
                                     float* __restrict__ z,
                                     int n_nodes) {
    __shared__ float xs[HIDDEN];
    int i = blockIdx.x;
    if (i >= n_nodes) return;
    int t = threadIdx.x;  // 0..255
    if (t < HIDDEN) xs[t] = x[(size_t)i * HIDDEN + t];
    __syncthreads();
    int j = t & (HIDDEN - 1);
    const float* __restrict__ Wb = W1 + ((t >= HIDDEN) ? (HIDDEN * HIDDEN) : 0);
    float acc = 0.f;
#pragma unroll 8
    for (int k4 = 0; k4 < HIDDEN / 4; ++k4) {
        float4 xv = ((const float4*)xs)[k4];
        acc = fmaf(xv.x, Wb[(k4 * 4 + 0) * HIDDEN + j], acc);
        acc = fmaf(xv.y, Wb[(k4 * 4 + 1) * HIDDEN + j], acc);
        acc = fmaf(xv.z, Wb[(k4 * 4 + 2) * HIDDEN + j], acc);
        acc = fmaf(xv.w, Wb[(k4 * 4 + 3) * HIDDEN + j], acc);
    }
    float* __restrict__ dst = (t < HIDDEN) ? y : z;
    dst[(size_t)i * HIDDEN + j] = acc;
}

// de_dot[b] = sum_j table[b][j] * W2[128+j]
__global__ void dedot_kernel(const float* __restrict__ table,
                             const float* __restrict__ W2,
                             float* __restrict__ de_dot) {
    int b = threadIdx.x;
    if (b >= NBUCKETS) return;
    float acc = 0.f;
    for (int j = 0; j < HIDDEN; ++j)
        acc = fmaf(table[b * HIDDEN + j], W2[HIDDEN + j], acc);
    de_dot[b] = acc;
}

// One wave (64 lanes) per edge; each lane handles 2 features.
__global__ void edge_kernel(const float* __restrict__ x,
                            const int* __restrict__ edge_index,
                            const int* __restrict__ distances,
                            const float* __restrict__ y,
                            const float* __restrict__ z,
                            const float* __restrict__ W2,
                            const float* __restrict__ de_dot,
                            float* __restrict__ agg,
                            float* __restrict__ att_agg,
                            int n_edges) {
    int lane = threadIdx.x & 63;
    int e = blockIdx.x * (blockDim.x >> 6) + (threadIdx.x >> 6);
    if (e >= n_edges) return;
    int s = edge_index[e];
    int t = edge_index[n_edges + e];
    int f0 = lane * 2;

    float2 yv = *(const float2*)(y + (size_t)s * HIDDEN + f0);
    float2 zv = *(const float2*)(z + (size_t)t * HIDDEN + f0);
    float2 wv = *(const float2*)(W2 + f0);

    float h0 = yv.x + zv.x;
    float h1 = yv.y + zv.y;
    h0 = (h0 > 0.f) ? h0 : 0.2f * h0;   // leaky_relu(0.2)
    h1 = (h1 > 0.f) ? h1 : 0.2f * h1;
    float partial = fmaf(h0, wv.x, h1 * wv.y);

#pragma unroll
    for (int off = 32; off > 0; off >>= 1)
        partial += __shfl_xor(partial, off, 64);

    float v = partial + de_dot[distances[e] / 50];
    float sig = 1.f / (1.f + __expf(-v));
    float att = __expf(sig);   // att in (1, e)

    float2 xv = *(const float2*)(x + (size_t)s * HIDDEN + f0);
    float* ap = agg + (size_t)t * HIDDEN + f0;
    atomicAdd(ap, att * xv.x);
    atomicAdd(ap + 1, att * xv.y);
    if (lane == 0) atomicAdd(att_agg + t, att);
}

// out = relu(agg / (att_agg + 1e-6)), float4-vectorized, in place on d_out.
__global__ void finalize_kernel(float* __restrict__ out,
                                const float* __restrict__ att_agg,
                                int total4) {
    int i = blockIdx.x * blockDim.x + threadIdx.x;
    if (i >= total4) return;
    float4 v = ((float4*)out)[i];
    float inv = 1.f / (att_agg[i >> 5] + 1e-6f);  // 32 float4s per node
    v.x = fmaxf(v.x * inv, 0.f);
    v.y = fmaxf(v.y * inv, 0.f);
    v.z = fmaxf(v.z * inv, 0.f);
    v.w = fmaxf(v.w * inv, 0.f);
    ((float4*)out)[i] = v;
}

extern "C" void kernel_launch(void* const* d_in, const int* in_sizes, int n_in,
                              void* d_out, int out_size, void* d_ws, size_t ws_size,
                              hipStream_t stream) {
    const float* x          = (const float*)d_in[0];
    const int*   edge_index = (const int*)d_in[1];
    const int*   distances  = (const int*)d_in[2];
    const float* W1         = (const float*)d_in[3];
    const float* W2         = (const float*)d_in[4];
    const float* table      = (const float*)d_in[5];

    int n_nodes = in_sizes[0] / HIDDEN;
    int n_edges = in_sizes[1] / 2;
    float* out = (float*)d_out;

    // Workspace layout (floats): [att_agg: n_nodes][de_dot: 32][y: n_nodes*128][z: n_nodes*128]
    float* ws      = (float*)d_ws;
    float* att_agg = ws;
    float* de_dot  = ws + n_nodes;
    float* y       = ws + n_nodes + 32;
    float* z       = y + (size_t)n_nodes * HIDDEN;

    // d_out doubles as agg accumulator; zero it (harness poisons with 0xAA).
    hipMemsetAsync(d_out, 0, (size_t)n_nodes * HIDDEN * sizeof(float), stream);
    hipMemsetAsync(att_agg, 0, (size_t)n_nodes * sizeof(float), stream);

    precompute_yz_kernel<<<n_nodes, 256, 0, stream>>>(x, W1, y, z, n_nodes);
    dedot_kernel<<<1, 32, 0, stream>>>(table, W2, de_dot);

    const int waves_per_block = 4;
    int eblocks = (n_edges + waves_per_block - 1) / waves_per_block;
    edge_kernel<<<eblocks, 64 * waves_per_block, 0, stream>>>(
        x, edge_index, distances, y, z, W2, de_dot, out, att_agg, n_edges);

    int total4 = n_nodes * HIDDEN / 4;
    finalize_kernel<<<(total4 + 255) / 256, 256, 0, stream>>>(out, att_agg, total4);
}

// Round 2
// 423.409 us; speedup vs baseline: 2.2094x; 2.2094x over previous
//
#include <hip/hip_runtime.h>

#define HIDDEN 128
#define NBUCKETS 20

// y[i][j] = sum_k x[i][k] * W1[k][j]        (threads 0..127)
// z[i][j] = sum_k x[i][k] * W1[128+k][j]    (threads 128..255)
__global__ void precompute_yz_kernel(const float* __restrict__ x,
                                     const float* __restrict__ W1,
                                     float* __restrict__ y,
                                     float* __restrict__ z,
                                     int n_nodes) {
    __shared__ float xs[HIDDEN];
    int i = blockIdx.x;
    if (i >= n_nodes) return;
    int t = threadIdx.x;  // 0..255
    if (t < HIDDEN) xs[t] = x[(size_t)i * HIDDEN + t];
    __syncthreads();
    int j = t & (HIDDEN - 1);
    const float* __restrict__ Wb = W1 + ((t >= HIDDEN) ? (HIDDEN * HIDDEN) : 0);
    float acc = 0.f;
#pragma unroll 8
    for (int k4 = 0; k4 < HIDDEN / 4; ++k4) {
        float4 xv = ((const float4*)xs)[k4];
        acc = fmaf(xv.x, Wb[(k4 * 4 + 0) * HIDDEN + j], acc);
        acc = fmaf(xv.y, Wb[(k4 * 4 + 1) * HIDDEN + j], acc);
        acc = fmaf(xv.z, Wb[(k4 * 4 + 2) * HIDDEN + j], acc);
        acc = fmaf(xv.w, Wb[(k4 * 4 + 3) * HIDDEN + j], acc);
    }
    float* __restrict__ dst = (t < HIDDEN) ? y : z;
    dst[(size_t)i * HIDDEN + j] = acc;
}

// de_dot[b] = sum_j table[b][j] * W2[128+j]
__global__ void dedot_kernel(const float* __restrict__ table,
                             const float* __restrict__ W2,
                             float* __restrict__ de_dot) {
    int b = threadIdx.x;
    if (b >= NBUCKETS) return;
    float acc = 0.f;
    for (int j = 0; j < HIDDEN; ++j)
        acc = fmaf(table[b * HIDDEN + j], W2[HIDDEN + j], acc);
    de_dot[b] = acc;
}

// Histogram of target degrees.
__global__ void count_kernel(const int* __restrict__ tgt,
                             int* __restrict__ cnt, int n_edges) {
    int e = blockIdx.x * blockDim.x + threadIdx.x;
    if (e < n_edges) atomicAdd(&cnt[tgt[e]], 1);
}

// Per-block exclusive prescan of cnt + per-block totals.
__global__ void scan_blocks_kernel(const int* __restrict__ cnt,
                                   int* __restrict__ prescan,
                                   int* __restrict__ partial,
                                   int n_nodes) {
    __shared__ int sh[256];
    int t = threadIdx.x;
    int i = blockIdx.x * 256 + t;
    int v = (i < n_nodes) ? cnt[i] : 0;
    sh[t] = v;
    __syncthreads();
    for (int d = 1; d < 256; d <<= 1) {
        int add = (t >= d) ? sh[t - d] : 0;
        __syncthreads();
        sh[t] += add;
        __syncthreads();
    }
    if (i < n_nodes) prescan[i] = sh[t] - v;
    if (t == 255) partial[blockIdx.x] = sh[t];
}

// Exclusive scan of block totals (nb <= 256).
__global__ void scan_partials_kernel(int* __restrict__ partial, int nb) {
    __shared__ int sh[256];
    int t = threadIdx.x;
    int v = (t < nb) ? partial[t] : 0;
    sh[t] = v;
    __syncthreads();
    for (int d = 1; d < 256; d <<= 1) {
        int add = (t >= d) ? sh[t - d] : 0;
        __syncthreads();
        sh[t] += add;
        __syncthreads();
    }
    if (t < nb) partial[t] = sh[t] - v;   // exclusive, in place
}

// Scatter edges into CSR order, pre-gathering src id and de_dot scalar.
__global__ void scatter_kernel(const int* __restrict__ edge_index,
                               const int* __restrict__ distances,
                               const int* __restrict__ prescan,
                               const int* __restrict__ partial,
                               const float* __restrict__ de_dot,
                               int* __restrict__ cursor,
                               int* __restrict__ csr_src,
                               float* __restrict__ csr_ded,
                               int n_edges) {
    int e = blockIdx.x * blockDim.x + threadIdx.x;
    if (e >= n_edges) return;
    int s = edge_index[e];
    int t = edge_index[n_edges + e];
    int base = prescan[t] + partial[t >> 8];
    int pos = atomicAdd(&cursor[t], 1);
    csr_src[base + pos] = s;
    csr_ded[base + pos] = de_dot[distances[e] / 50];
}

// One wave per node: fused attention + aggregation + normalize + relu.
__global__ void aggregate_kernel(const float* __restrict__ x,
                                 const float* __restrict__ y,
                                 const float* __restrict__ z,
                                 const float* __restrict__ W2,
                                 const int* __restrict__ csr_src,
                                 const float* __restrict__ csr_ded,
                                 const int* __restrict__ prescan,
                                 const int* __restrict__ partial,
                                 const int* __restrict__ cnt,
                                 float* __restrict__ out,
                                 int n_nodes) {
    int lane = threadIdx.x & 63;
    int t = blockIdx.x * (blockDim.x >> 6) + (threadIdx.x >> 6);
    if (t >= n_nodes) return;

    int base = prescan[t] + partial[t >> 8];
    int deg = cnt[t];
    int f0 = lane * 2;

    float2 zv = *(const float2*)(z + (size_t)t * HIDDEN + f0);
    float2 wv = *(const float2*)(W2 + f0);

    float acc0 = 0.f, acc1 = 0.f, attsum = 0.f;

    for (int b = 0; b < deg; b += 64) {
        int nb = min(64, deg - b);
        int sv = 0;
        float dedv = 0.f;
        if (lane < nb) {
            sv = csr_src[base + b + lane];     // coalesced
            dedv = csr_ded[base + b + lane];   // coalesced
        }
        for (int j = 0; j < nb; ++j) {
            int sj = __shfl(sv, j, 64);
            float dedj = __shfl(dedv, j, 64);
            float2 yv = *(const float2*)(y + (size_t)sj * HIDDEN + f0);
            float2 xv = *(const float2*)(x + (size_t)sj * HIDDEN + f0);
            float h0 = yv.x + zv.x;
            float h1 = yv.y + zv.y;
            h0 = (h0 > 0.f) ? h0 : 0.2f * h0;
            h1 = (h1 > 0.f) ? h1 : 0.2f * h1;
            float p = fmaf(h0, wv.x, h1 * wv.y);
#pragma unroll
            for (int off = 32; off > 0; off >>= 1)
                p += __shfl_xor(p, off, 64);
            float v = p + dedj;
            float sig = 1.f / (1.f + __expf(-v));
            float att = __expf(sig);
            acc0 = fmaf(att, xv.x, acc0);
            acc1 = fmaf(att, xv.y, acc1);
            attsum += att;   // wave-uniform
        }
    }
    float inv = 1.f / (attsum + 1e-6f);
    float* op = out + (size_t)t * HIDDEN + f0;
    op[0] = fmaxf(acc0 * inv, 0.f);
    op[1] = fmaxf(acc1 * inv, 0.f);
}

extern "C" void kernel_launch(void* const* d_in, const int* in_sizes, int n_in,
                              void* d_out, int out_size, void* d_ws, size_t ws_size,
                              hipStream_t stream) {
    const float* x          = (const float*)d_in[0];
    const int*   edge_index = (const int*)d_in[1];
    const int*   distances  = (const int*)d_in[2];
    const float* W1         = (const float*)d_in[3];
    const float* W2         = (const float*)d_in[4];
    const float* table      = (const float*)d_in[5];

    int n_nodes = in_sizes[0] / HIDDEN;
    int n_edges = in_sizes[1] / 2;
    float* out = (float*)d_out;

    // Workspace layout
    int* ws_i = (int*)d_ws;
    int* cnt      = ws_i;                       // n_nodes
    int* cursor   = cnt + n_nodes;              // n_nodes   (adjacent -> one memset)
    int* prescan  = cursor + n_nodes;           // n_nodes
    int* partial  = prescan + n_nodes;          // 256
    int* csr_src  = partial + 256;              // n_edges
    float* csr_ded = (float*)(csr_src + n_edges); // n_edges
    float* de_dot  = csr_ded + n_edges;         // 32
    float* y       = de_dot + 32;               // n_nodes*128
    float* z       = y + (size_t)n_nodes * HIDDEN;

    hipMemsetAsync(cnt, 0, (size_t)2 * n_nodes * sizeof(int), stream);

    precompute_yz_kernel<<<n_nodes, 256, 0, stream>>>(x, W1, y, z, n_nodes);
    dedot_kernel<<<1, 32, 0, stream>>>(table, W2, de_dot);

    const int* tgt = edge_index + n_edges;
    count_kernel<<<(n_edges + 255) / 256, 256, 0, stream>>>(tgt, cnt, n_edges);

    int nb = (n_nodes + 255) / 256;
    scan_blocks_kernel<<<nb, 256, 0, stream>>>(cnt, prescan, partial, n_nodes);
    scan_partials_kernel<<<1, 256, 0, stream>>>(partial, nb);

    scatter_kernel<<<(n_edges + 255) / 256, 256, 0, stream>>>(
        edge_index, distances, prescan, partial, de_dot, cursor,
        csr_src, csr_ded, n_edges);

    const int waves_per_block = 4;
    int ablocks = (n_nodes + waves_per_block - 1) / waves_per_block;
    aggregate_kernel<<<ablocks, 64 * waves_per_block, 0, stream>>>(
        x, y, z, W2, csr_src, csr_ded, prescan, partial, cnt, out, n_nodes);
}

// Round 3
// 312.818 us; speedup vs baseline: 2.9904x; 1.3535x over previous
//
#include <hip/hip_runtime.h>

#define HIDDEN 128
#define NBUCKETS 20
#define ROWS 32

// Register-blocked skinny GEMM: each block computes y[base..base+31][:] and
// z[base..base+31][:] (256 output cols = 128 y + 128 z; one col per thread).
// x-tile staged in LDS (broadcast reads); W1 streamed from L2 once per block.
__global__ void precompute_yz_kernel(const float* __restrict__ x,
                                     const float* __restrict__ W1,
                                     float* __restrict__ y,
                                     float* __restrict__ z,
                                     int n_nodes) {
    __shared__ float xs[ROWS][HIDDEN];
    int base = blockIdx.x * ROWS;
    int t = threadIdx.x;  // 0..255

    // Cooperative float4 tile load, zero-padded past n_nodes.
    float4* xsf4 = (float4*)xs;
    const float4* xf4 = (const float4*)(x + (size_t)base * HIDDEN);
    const int total4 = ROWS * HIDDEN / 4;  // 1024
#pragma unroll
    for (int i = t; i < total4; i += 256) {
        int node = base + (i >> 5);  // 32 float4s per row
        float4 v = make_float4(0.f, 0.f, 0.f, 0.f);
        if (node < n_nodes) v = xf4[i];
        xsf4[i] = v;
    }
    __syncthreads();

    int j = t & (HIDDEN - 1);
    int half = t >> 7;  // 0 -> y (W1 rows 0..127), 1 -> z (W1 rows 128..255)
    const float* __restrict__ Wb = W1 + half * HIDDEN * HIDDEN;

    float acc[ROWS];
#pragma unroll
    for (int r = 0; r < ROWS; ++r) acc[r] = 0.f;

    for (int k4 = 0; k4 < HIDDEN / 4; ++k4) {
        int k = k4 * 4;
        float w0 = Wb[(k + 0) * HIDDEN + j];
        float w1 = Wb[(k + 1) * HIDDEN + j];
        float w2 = Wb[(k + 2) * HIDDEN + j];
        float w3 = Wb[(k + 3) * HIDDEN + j];
#pragma unroll
        for (int r = 0; r < ROWS; ++r) {
            float4 xv = *(const float4*)&xs[r][k];
            acc[r] = fmaf(xv.x, w0, acc[r]);
            acc[r] = fmaf(xv.y, w1, acc[r]);
            acc[r] = fmaf(xv.z, w2, acc[r]);
            acc[r] = fmaf(xv.w, w3, acc[r]);
        }
    }

    float* __restrict__ dst = half ? z : y;
#pragma unroll
    for (int r = 0; r < ROWS; ++r) {
        int node = base + r;
        if (node < n_nodes) dst[(size_t)node * HIDDEN + j] = acc[r];
    }
}

// de_dot[b] = sum_j table[b][j] * W2[128+j]
__global__ void dedot_kernel(const float* __restrict__ table,
                             const float* __restrict__ W2,
                             float* __restrict__ de_dot) {
    int b = threadIdx.x;
    if (b >= NBUCKETS) return;
    float acc = 0.f;
    for (int j = 0; j < HIDDEN; ++j)
        acc = fmaf(table[b * HIDDEN + j], W2[HIDDEN + j], acc);
    de_dot[b] = acc;
}

// Histogram of target degrees.
__global__ void count_kernel(const int* __restrict__ tgt,
                             int* __restrict__ cnt, int n_edges) {
    int e = blockIdx.x * blockDim.x + threadIdx.x;
    if (e < n_edges) atomicAdd(&cnt[tgt[e]], 1);
}

// Per-block exclusive prescan of cnt + per-block totals.
__global__ void scan_blocks_kernel(const int* __restrict__ cnt,
                                   int* __restrict__ prescan,
                                   int* __restrict__ partial,
                                   int n_nodes) {
    __shared__ int sh[256];
    int t = threadIdx.x;
    int i = blockIdx.x * 256 + t;
    int v = (i < n_nodes) ? cnt[i] : 0;
    sh[t] = v;
    __syncthreads();
    for (int d = 1; d < 256; d <<= 1) {
        int add = (t >= d) ? sh[t - d] : 0;
        __syncthreads();
        sh[t] += add;
        __syncthreads();
    }
    if (i < n_nodes) prescan[i] = sh[t] - v;
    if (t == 255) partial[blockIdx.x] = sh[t];
}

// Exclusive scan of block totals (nb <= 256).
__global__ void scan_partials_kernel(int* __restrict__ partial, int nb) {
    __shared__ int sh[256];
    int t = threadIdx.x;
    int v = (t < nb) ? partial[t] : 0;
    sh[t] = v;
    __syncthreads();
    for (int d = 1; d < 256; d <<= 1) {
        int add = (t >= d) ? sh[t - d] : 0;
        __syncthreads();
        sh[t] += add;
        __syncthreads();
    }
    if (t < nb) partial[t] = sh[t] - v;   // exclusive, in place
}

// Scatter edges into CSR order, pre-gathering src id and de_dot scalar.
__global__ void scatter_kernel(const int* __restrict__ edge_index,
                               const int* __restrict__ distances,
                               const int* __restrict__ prescan,
                               const int* __restrict__ partial,
                               const float* __restrict__ de_dot,
                               int* __restrict__ cursor,
                               int* __restrict__ csr_src,
                               float* __restrict__ csr_ded,
                               int n_edges) {
    int e = blockIdx.x * blockDim.x + threadIdx.x;
    if (e >= n_edges) return;
    int s = edge_index[e];
    int t = edge_index[n_edges + e];
    int base = prescan[t] + partial[t >> 8];
    int pos = atomicAdd(&cursor[t], 1);
    csr_src[base + pos] = s;
    csr_ded[base + pos] = de_dot[distances[e] / 50];
}

// One wave per node: fused attention + aggregation + normalize + relu.
__global__ void aggregate_kernel(const float* __restrict__ x,
                                 const float* __restrict__ y,
                                 const float* __restrict__ z,
                                 const float* __restrict__ W2,
                                 const int* __restrict__ csr_src,
                                 const float* __restrict__ csr_ded,
                                 const int* __restrict__ prescan,
                                 const int* __restrict__ partial,
                                 const int* __restrict__ cnt,
                                 float* __restrict__ out,
                                 int n_nodes) {
    int lane = threadIdx.x & 63;
    int t = blockIdx.x * (blockDim.x >> 6) + (threadIdx.x >> 6);
    if (t >= n_nodes) return;

    int base = prescan[t] + partial[t >> 8];
    int deg = cnt[t];
    int f0 = lane * 2;

    float2 zv = *(const float2*)(z + (size_t)t * HIDDEN + f0);
    float2 wv = *(const float2*)(W2 + f0);

    float acc0 = 0.f, acc1 = 0.f, attsum = 0.f;

    for (int b = 0; b < deg; b += 64) {
        int nb = min(64, deg - b);
        int sv = 0;
        float dedv = 0.f;
        if (lane < nb) {
            sv = csr_src[base + b + lane];     // coalesced
            dedv = csr_ded[base + b + lane];   // coalesced
        }
        for (int j = 0; j < nb; ++j) {
            int sj = __shfl(sv, j, 64);
            float dedj = __shfl(dedv, j, 64);
            float2 yv = *(const float2*)(y + (size_t)sj * HIDDEN + f0);
            float2 xv = *(const float2*)(x + (size_t)sj * HIDDEN + f0);
            float h0 = yv.x + zv.x;
            float h1 = yv.y + zv.y;
            h0 = (h0 > 0.f) ? h0 : 0.2f * h0;
            h1 = (h1 > 0.f) ? h1 : 0.2f * h1;
            float p = fmaf(h0, wv.x, h1 * wv.y);
#pragma unroll
            for (int off = 32; off > 0; off >>= 1)
                p += __shfl_xor(p, off, 64);
            float v = p + dedj;
            float sig = 1.f / (1.f + __expf(-v));
            float att = __expf(sig);
            acc0 = fmaf(att, xv.x, acc0);
            acc1 = fmaf(att, xv.y, acc1);
            attsum += att;   // wave-uniform
        }
    }
    float inv = 1.f / (attsum + 1e-6f);
    float* op = out + (size_t)t * HIDDEN + f0;
    op[0] = fmaxf(acc0 * inv, 0.f);
    op[1] = fmaxf(acc1 * inv, 0.f);
}

extern "C" void kernel_launch(void* const* d_in, const int* in_sizes, int n_in,
                              void* d_out, int out_size, void* d_ws, size_t ws_size,
                              hipStream_t stream) {
    const float* x          = (const float*)d_in[0];
    const int*   edge_index = (const int*)d_in[1];
    const int*   distances  = (const int*)d_in[2];
    const float* W1         = (const float*)d_in[3];
    const float* W2         = (const float*)d_in[4];
    const float* table      = (const float*)d_in[5];

    int n_nodes = in_sizes[0] / HIDDEN;
    int n_edges = in_sizes[1] / 2;
    float* out = (float*)d_out;

    // Workspace layout
    int* ws_i = (int*)d_ws;
    int* cnt      = ws_i;                       // n_nodes
    int* cursor   = cnt + n_nodes;              // n_nodes   (adjacent -> one memset)
    int* prescan  = cursor + n_nodes;           // n_nodes
    int* partial  = prescan + n_nodes;          // 256
    int* csr_src  = partial + 256;              // n_edges
    float* csr_ded = (float*)(csr_src + n_edges); // n_edges
    float* de_dot  = csr_ded + n_edges;         // 32
    float* y       = de_dot + 32;               // n_nodes*128
    float* z       = y + (size_t)n_nodes * HIDDEN;

    hipMemsetAsync(cnt, 0, (size_t)2 * n_nodes * sizeof(int), stream);

    int pblocks = (n_nodes + ROWS - 1) / ROWS;
    precompute_yz_kernel<<<pblocks, 256, 0, stream>>>(x, W1, y, z, n_nodes);
    dedot_kernel<<<1, 32, 0, stream>>>(table, W2, de_dot);

    const int* tgt = edge_index + n_edges;
    count_kernel<<<(n_edges + 255) / 256, 256, 0, stream>>>(tgt, cnt, n_edges);

    int nb = (n_nodes + 255) / 256;
    scan_blocks_kernel<<<nb, 256, 0, stream>>>(cnt, prescan, partial, n_nodes);
    scan_partials_kernel<<<1, 256, 0, stream>>>(partial, nb);

    scatter_kernel<<<(n_edges + 255) / 256, 256, 0, stream>>>(
        edge_index, distances, prescan, partial, de_dot, cursor,
        csr_src, csr_ded, n_edges);

    const int waves_per_block = 4;
    int ablocks = (n_nodes + waves_per_block - 1) / waves_per_block;
    aggregate_kernel<<<ablocks, 64 * waves_per_block, 0, stream>>>(
        x, y, z, W2, csr_src, csr_ded, prescan, partial, cnt, out, n_nodes);
}